// Round 2
// baseline (1904.951 us; speedup 1.0000x reference)
//
#include <hip/hip_runtime.h>
#include <math.h>

// ---------------- problem dims ----------------
#define NB 32
#define NT 64
#define NA 2
#define NE 64
#define ND 128
#define NS 32
#define NF 2048  // NB*NT frames

// ---------------- output float offsets ----------------
#define OUT_ZS    2097152
#define OUT_PRM   (OUT_ZS + 65536)
#define OUT_PRLS  (OUT_PRM + 65536)
#define OUT_PM    (OUT_PRLS + 65536)
#define OUT_PLS   (OUT_PM + 65536)
#define OUT_HF    (OUT_PLS + 65536)

// ---------------- workspace float offsets (28,038,144 floats = 112.2 MB) ---
#define WS_X1    0          // 2048*32*16*16 = 16777216 (conv1 out; reused: deconv2 out)
#define WS_X2    16777216   // 2048*64*8*8   =  8388608 (conv2 out; reused: deconv1 out)
#define WS_X3    25165824   // 2048*64*4*4   =  2097152 (conv3 out; reused: dec-lin out)
#define WS_EMB   27262976   // 2048*64
#define WS_HS    27394048   // 64*32*128 pre-update h per step
#define WS_ENCT  27656192   // enc_pw^T  (1024x64)
#define WS_DECT  27721728   // dec_pw^T  (160x1024)
#define WS_POS1T 27885568   // 192x128
#define WS_POS2T 27910144   // 128x128
#define WS_POS3T 27926528   // 128x64
#define WS_PRI1T 27934720   // 130x128
#define WS_PRI2T 27951360   // 128x128
#define WS_PRI3T 27967744   // 128x64
#define WS_WIHT  27975936   // 34x384
#define WS_WHHT  27988992   // 128x384

// ==================== weight transposes ====================
struct TP { const float* src; float* dst; int rows; int cols; };
struct TPAll { TP m[10]; };

__global__ __launch_bounds__(256) void k_transpose(TPAll a) {
  TP tp = a.m[blockIdx.y];
  const int n = tp.rows * tp.cols;
  for (int i = blockIdx.x * 256 + threadIdx.x; i < n; i += gridDim.x * 256) {
    int r = i / tp.cols, c = i - r * tp.cols;
    tp.dst[c * tp.rows + r] = tp.src[i];
  }
}

// ==================== encoder conv1: 1x32x32 -> 32x16x16, s2 p1 relu =======
__global__ __launch_bounds__(256) void k_conv1(const float* __restrict__ obs,
    const float* __restrict__ w, const float* __restrict__ bias,
    float* __restrict__ out) {
  __shared__ float sIn[32 * 33];
  __shared__ float sW[512];
  __shared__ float sB[32];
  const int f = blockIdx.x, tid = threadIdx.x;
  const float* in = obs + f * 1024;
  for (int i = tid; i < 1024; i += 256) sIn[(i >> 5) * 33 + (i & 31)] = in[i];
  for (int i = tid; i < 512; i += 256) sW[i] = w[i];
  if (tid < 32) sB[tid] = bias[tid];
  __syncthreads();
  float* outf = out + f * 8192;
  for (int r = tid; r < 512; r += 256) {       // r = oc*16 + oy
    const int oc = r >> 4, oy = r & 15;
    float acc[16];
    const float bv = sB[oc];
#pragma unroll
    for (int j = 0; j < 16; j++) acc[j] = bv;
#pragma unroll
    for (int ky = 0; ky < 4; ky++) {
      const int iy = 2 * oy + ky - 1;
      if (iy < 0 || iy >= 32) continue;
#pragma unroll
      for (int kx = 0; kx < 4; kx++) {
        const float wv = sW[oc * 16 + ky * 4 + kx];
#pragma unroll
        for (int j = 0; j < 16; j++) {
          const int ix = 2 * j + kx - 1;
          if (ix >= 0 && ix < 32) acc[j] += wv * sIn[iy * 33 + ix];
        }
      }
    }
#pragma unroll
    for (int j = 0; j < 16; j++) outf[r * 16 + j] = fmaxf(acc[j], 0.f);
  }
}

// ==================== generic stride-2 conv (k4 p1, relu) ==================
// one frame per block; weights [OC][IC][4][4]; register tile TOC x TPX.
template<int IC, int IH, int IW, int OC, int TOC, int TPX, int CH>
__global__ __launch_bounds__(256) void k_conv_s2(const float* __restrict__ x,
    const float* __restrict__ w, const float* __restrict__ bias,
    float* __restrict__ y) {
  constexpr int OH = IH / 2, OW = IW / 2, NPX = OH * OW;
  constexpr int IWP = IW + 1, OCP = OC + 1;
  constexpr int NPXG = NPX / TPX, NXG = OW / TPX;
  static_assert((OC / TOC) * NPXG == 256, "thread mapping");
  __shared__ float sIn[IC * IH * IWP];
  __shared__ float sW[CH * 16 * OCP];
  const int f = blockIdx.x, tid = threadIdx.x;
  const float* xf = x + (size_t)f * IC * IH * IW;
  for (int i = tid; i < IC * IH * IW; i += 256) {
    const int ic = i / (IH * IW), rem = i - ic * (IH * IW);
    sIn[ic * (IH * IWP) + (rem / IW) * IWP + rem % IW] = xf[i];
  }
  const int ocg = tid / NPXG, pxg = tid - ocg * NPXG;
  const int oc0 = ocg * TOC;
  const int oy = pxg / NXG, ox0 = (pxg - oy * NXG) * TPX;
  float acc[TOC][TPX];
#pragma unroll
  for (int a = 0; a < TOC; a++) {
    const float bv = bias[oc0 + a];
#pragma unroll
    for (int j = 0; j < TPX; j++) acc[a][j] = bv;
  }
  for (int icb = 0; icb < IC; icb += CH) {
    __syncthreads();
    for (int s = tid; s < CH * 16 * OC; s += 256) {
      const int oc = s / (CH * 16), r = s - oc * (CH * 16);
      sW[r * OCP + oc] = w[(oc * IC + icb) * 16 + r];
    }
    __syncthreads();
    for (int icc = 0; icc < CH; icc++) {
      const float* inb = &sIn[(icb + icc) * (IH * IWP)];
      const float* wb = &sW[icc * 16 * OCP];
#pragma unroll
      for (int ky = 0; ky < 4; ky++) {
        const int iy = 2 * oy + ky - 1;
        if (iy < 0 || iy >= IH) continue;
        const float* row = inb + iy * IWP;
#pragma unroll
        for (int kx = 0; kx < 4; kx++) {
          float wv[TOC];
#pragma unroll
          for (int a = 0; a < TOC; a++) wv[a] = wb[(ky * 4 + kx) * OCP + oc0 + a];
#pragma unroll
          for (int j = 0; j < TPX; j++) {
            const int ix = 2 * (ox0 + j) + kx - 1;
            if (ix >= 0 && ix < IW) {
              const float xv = row[ix];
#pragma unroll
              for (int a = 0; a < TOC; a++) acc[a][j] += wv[a] * xv;
            }
          }
        }
      }
    }
  }
  float* yf = y + (size_t)f * OC * NPX;
#pragma unroll
  for (int a = 0; a < TOC; a++)
#pragma unroll
    for (int j = 0; j < TPX; j++)
      yf[(oc0 + a) * NPX + oy * OW + ox0 + j] = fmaxf(acc[a][j], 0.f);
}

// ==================== generic stride-2 deconv (ConvTranspose2d k4 s2 p1) ===
// weights [IC][OC][4][4]; ACT 1=relu 2=sigmoid; REMAP: frame t*NB+b -> b*NT+t
template<int IC, int IH, int IW, int OC, int TOC, int TPX, int CH, int ACT, int REMAP>
__global__ __launch_bounds__(256) void k_deconv_s2(const float* __restrict__ x,
    const float* __restrict__ w, const float* __restrict__ bias,
    float* __restrict__ y) {
  constexpr int OH = IH * 2, OW = IW * 2, NPX = OH * OW;
  constexpr int IWP = IW + 1, OCP = OC + 1;
  constexpr int NQ = (OW / 2) / TPX;
  constexpr int NPXG = OH * 2 * NQ;
  static_assert((OC / TOC) * NPXG == 256, "thread mapping");
  __shared__ float sIn[IC * IH * IWP];
  __shared__ float sW[CH * 16 * OCP];
  const int f = blockIdx.x, tid = threadIdx.x;
  const float* xf = x + (size_t)f * IC * IH * IW;
  for (int i = tid; i < IC * IH * IW; i += 256) {
    const int ic = i / (IH * IW), rem = i - ic * (IH * IW);
    sIn[ic * (IH * IWP) + (rem / IW) * IWP + rem % IW] = xf[i];
  }
  const int ocg = tid / NPXG, pxg = tid - ocg * NPXG;
  const int oc0 = ocg * TOC;
  const int oy = pxg / (2 * NQ);
  const int rem2 = pxg - oy * (2 * NQ);
  const int c = rem2 / NQ, q = rem2 - c * NQ;
  const int py = (oy + 1) & 1, pc = (c + 1) & 1;
  float acc[TOC][TPX];
#pragma unroll
  for (int a = 0; a < TOC; a++) {
    const float bv = bias[oc0 + a];
#pragma unroll
    for (int j = 0; j < TPX; j++) acc[a][j] = bv;
  }
  for (int icb = 0; icb < IC; icb += CH) {
    __syncthreads();
    {
      const float* wb = w + (size_t)icb * OC * 16;
      for (int s = tid; s < CH * OC * 16; s += 256) {
        const int icc = s / (OC * 16), r = s - icc * (OC * 16);
        const int oc = r / 16, tap = r & 15;
        sW[(icc * 16 + tap) * OCP + oc] = wb[s];
      }
    }
    __syncthreads();
    for (int icc = 0; icc < CH; icc++) {
      const float* inb = &sIn[(icb + icc) * (IH * IWP)];
      const float* wb = &sW[icc * 16 * OCP];
#pragma unroll
      for (int t2 = 0; t2 < 2; t2++) {
        const int ky = py + 2 * t2;
        const int iy = (oy + 1 - ky) >> 1;
        if (iy < 0 || iy >= IH) continue;
        const float* row = inb + iy * IWP;
#pragma unroll
        for (int t3 = 0; t3 < 2; t3++) {
          const int kx = pc + 2 * t3;
          const int ixb = (c + 1 - kx) >> 1;
          float wv[TOC];
#pragma unroll
          for (int a = 0; a < TOC; a++) wv[a] = wb[(ky * 4 + kx) * OCP + oc0 + a];
#pragma unroll
          for (int j = 0; j < TPX; j++) {
            const int ix = ixb + q * TPX + j;
            if (ix >= 0 && ix < IW) {
              const float xv = row[ix];
#pragma unroll
              for (int a = 0; a < TOC; a++) acc[a][j] += wv[a] * xv;
            }
          }
        }
      }
    }
  }
  int fo = f;
  if (REMAP) fo = (f & (NB - 1)) * NT + (f >> 5);
  float* yf = y + (size_t)fo * OC * NPX;
#pragma unroll
  for (int a = 0; a < TOC; a++)
#pragma unroll
    for (int j = 0; j < TPX; j++) {
      float v = acc[a][j];
      if (ACT == 1) v = fmaxf(v, 0.f);
      if (ACT == 2) v = 1.f / (1.f + expf(-v));
      yf[(oc0 + a) * NPX + oy * OW + (c + 2 * (q * TPX + j))] = v;
    }
}

// ==================== encoder linear: (2048,1024) -> (2048,64) =============
__global__ __launch_bounds__(256) void k_enclin(const float* __restrict__ x,
    const float* __restrict__ wT, const float* __restrict__ bias,
    float* __restrict__ emb) {
  __shared__ float sX[1024];
  __shared__ float sP[256];
  const int f = blockIdx.x, tid = threadIdx.x;
  for (int i = tid; i < 1024; i += 256) sX[i] = x[(size_t)f * 1024 + i];
  __syncthreads();
  const int o = tid & 63, s = tid >> 6;
  float acc = 0.f;
  const int k0 = s * 256;
  for (int k = k0; k < k0 + 256; k++) acc += wT[k * 64 + o] * sX[k];
  sP[tid] = acc;
  __syncthreads();
  if (tid < 64)
    emb[(size_t)f * 64 + tid] =
        sP[tid] + sP[tid + 64] + sP[tid + 128] + sP[tid + 192] + bias[tid];
}

// ==================== decoder linear: (2048,160) -> (2048,1024) ============
// frame r = t*NB + b ; h from hs ws, z from zs output
__global__ __launch_bounds__(256) void k_declin(const float* __restrict__ hs,
    const float* __restrict__ zs, const float* __restrict__ wT,
    const float* __restrict__ bias, float* __restrict__ y) {
  __shared__ float sX[160];
  const int f = blockIdx.x, tid = threadIdx.x;
  const int t = f >> 5, b = f & 31;
  if (tid < 128) sX[tid] = hs[(size_t)(t * 32 + b) * 128 + tid];
  else if (tid < 160) sX[tid] = zs[(size_t)(b * 64 + t) * 32 + (tid - 128)];
  __syncthreads();
  float acc[4];
#pragma unroll
  for (int i = 0; i < 4; i++) acc[i] = bias[i * 256 + tid];
  for (int k = 0; k < 160; k++) {
    const float xv = sX[k];
#pragma unroll
    for (int i = 0; i < 4; i++) acc[i] += wT[k * 1024 + i * 256 + tid] * xv;
  }
#pragma unroll
  for (int i = 0; i < 4; i++) y[(size_t)f * 1024 + i * 256 + tid] = acc[i];
}

// ==================== recurrent RSSM core ==================================
// one block per batch element; 64 sequential steps with stage barriers.
__global__ __launch_bounds__(256) void k_rssm(
    const float* __restrict__ emb, const float* __restrict__ act,
    const float* __restrict__ noise,
    const float* __restrict__ pw1, const float* __restrict__ pb1,
    const float* __restrict__ pw2, const float* __restrict__ pb2,
    const float* __restrict__ pw3, const float* __restrict__ pb3,
    const float* __restrict__ qw1, const float* __restrict__ qb1,
    const float* __restrict__ qw2, const float* __restrict__ qb2,
    const float* __restrict__ qw3, const float* __restrict__ qb3,
    const float* __restrict__ wih, const float* __restrict__ whh,
    const float* __restrict__ bih, const float* __restrict__ bhh,
    float* __restrict__ hs, float* __restrict__ out) {
  const int b = blockIdx.x, tid = threadIdx.x;
  __shared__ float sH[128], sE[64], sA[2], sEps[32];
  __shared__ float sL1[256], sL2[256];
  __shared__ float sPm[32], sPls[32], sPrm[32], sPrls[32], sZ[32];
  __shared__ float sGh[384], sGi[384];
  if (tid < 128) sH[tid] = 0.f;

  for (int t = 0; t < 64; t++) {
    __syncthreads();  // sH stable; previous step fully consumed
    if (tid < 64) sE[tid] = emb[(size_t)(b * 64 + t) * 64 + tid];
    else if (tid < 66) sA[tid - 64] = act[(size_t)(b * 64 + t) * 2 + (tid - 64)];
    else if (tid < 98) sEps[tid - 66] = noise[(size_t)(t * 32 + b) * 32 + (tid - 66)];
    if (tid < 128) hs[(size_t)(t * 32 + b) * 128 + tid] = sH[tid];
    __syncthreads();
    // ---- stage A: pos-l1, pri-l1, gh = h @ Whh^T + bhh
    if (tid < 128) {
      const int j = tid;
      float a = pb1[j];
      for (int k = 0; k < 192; k++) {
        const float xv = (k < 128) ? sH[k] : sE[k - 128];
        a += pw1[k * 128 + j] * xv;
      }
      sL1[j] = (a > 0.f) ? a : expm1f(a);
      float g = bhh[j];
      for (int k = 0; k < 128; k++) g += whh[k * 384 + j] * sH[k];
      sGh[j] = g;
    } else {
      const int j = tid - 128;
      float a = qb1[j];
      for (int k = 0; k < 130; k++) {
        const float xv = (k < 128) ? sH[k] : sA[k - 128];
        a += qw1[k * 128 + j] * xv;
      }
      sL1[128 + j] = (a > 0.f) ? a : expm1f(a);
      const int j1 = 128 + 2 * j, j2 = j1 + 1;
      float g1 = bhh[j1], g2 = bhh[j2];
      for (int k = 0; k < 128; k++) {
        const float hv = sH[k];
        g1 += whh[k * 384 + j1] * hv;
        g2 += whh[k * 384 + j2] * hv;
      }
      sGh[j1] = g1;
      sGh[j2] = g2;
    }
    __syncthreads();
    // ---- stage B: pos-l2 / pri-l2
    {
      const int j = tid & 127;
      const bool pri = tid >= 128;
      const float* wT = pri ? qw2 : pw2;
      const float* bb = pri ? qb2 : pb2;
      const float* xin = pri ? (sL1 + 128) : sL1;
      float a = bb[j];
      for (int k = 0; k < 128; k++) a += wT[k * 128 + j] * xin[k];
      sL2[tid] = (a > 0.f) ? a : expm1f(a);
    }
    __syncthreads();
    // ---- stage C: pos-l3 / pri-l3
    if (tid < 128) {
      const int j = tid & 63;
      const bool pri = tid >= 64;
      const float* wT = pri ? qw3 : pw3;
      const float* bb = pri ? qb3 : pb3;
      const float* xin = pri ? (sL2 + 128) : sL2;
      float a = bb[j];
      for (int k = 0; k < 128; k++) a += wT[k * 64 + j] * xin[k];
      if (j < 32) (pri ? sPrm : sPm)[j] = a;
      else (pri ? sPrls : sPls)[j - 32] = fminf(fmaxf(a, -5.f), 2.f);
    }
    __syncthreads();
    // ---- z + latent outputs
    if (tid < 32) {
      const float z = sPm[tid] + expf(sPls[tid]) * sEps[tid];
      sZ[tid] = z;
      const int o = (b * 64 + t) * 32 + tid;
      out[OUT_ZS + o] = z;
      out[OUT_PM + o] = sPm[tid];
      out[OUT_PLS + o] = sPls[tid];
      out[OUT_PRM + o] = sPrm[tid];
      out[OUT_PRLS + o] = sPrls[tid];
    }
    __syncthreads();
    // ---- stage D: gi = [z,a] @ Wih^T + bih
    for (int j = tid; j < 384; j += 256) {
      float a = bih[j];
      for (int k = 0; k < 34; k++) {
        const float xv = (k < 32) ? sZ[k] : sA[k - 32];
        a += wih[k * 384 + j] * xv;
      }
      sGi[j] = a;
    }
    __syncthreads();
    // ---- stage E: GRU gates, h update
    if (tid < 128) {
      const int j = tid;
      const float r = 1.f / (1.f + expf(-(sGi[j] + sGh[j])));
      const float u = 1.f / (1.f + expf(-(sGi[128 + j] + sGh[128 + j])));
      const float n = tanhf(sGi[256 + j] + r * sGh[256 + j]);
      sH[j] = (1.f - u) * n + u * sH[j];
    }
  }
  __syncthreads();
  if (tid < 128) out[OUT_HF + b * 128 + tid] = sH[tid];
}

// ==================== launch ====================
extern "C" void kernel_launch(void* const* d_in, const int* in_sizes, int n_in,
                              void* d_out, int out_size, void* d_ws, size_t ws_size,
                              hipStream_t stream) {
  const float* obs = (const float*)d_in[0];
  const float* actions = (const float*)d_in[1];
  const float* noise = (const float*)d_in[2];
  const float* enc_w1 = (const float*)d_in[3];
  const float* enc_b1 = (const float*)d_in[4];
  const float* enc_w2 = (const float*)d_in[5];
  const float* enc_b2 = (const float*)d_in[6];
  const float* enc_w3 = (const float*)d_in[7];
  const float* enc_b3 = (const float*)d_in[8];
  const float* enc_pw = (const float*)d_in[9];
  const float* enc_pb = (const float*)d_in[10];
  const float* dec_pw = (const float*)d_in[11];
  const float* dec_pb = (const float*)d_in[12];
  const float* dec_w1 = (const float*)d_in[13];
  const float* dec_b1 = (const float*)d_in[14];
  const float* dec_w2 = (const float*)d_in[15];
  const float* dec_b2 = (const float*)d_in[16];
  const float* dec_w3 = (const float*)d_in[17];
  const float* dec_b3 = (const float*)d_in[18];
  const float* gru_wih = (const float*)d_in[19];
  const float* gru_whh = (const float*)d_in[20];
  const float* gru_bih = (const float*)d_in[21];
  const float* gru_bhh = (const float*)d_in[22];
  const float* pri_w1 = (const float*)d_in[23];
  const float* pri_b1 = (const float*)d_in[24];
  const float* pri_w2 = (const float*)d_in[25];
  const float* pri_b2 = (const float*)d_in[26];
  const float* pri_w3 = (const float*)d_in[27];
  const float* pri_b3 = (const float*)d_in[28];
  const float* pos_w1 = (const float*)d_in[29];
  const float* pos_b1 = (const float*)d_in[30];
  const float* pos_w2 = (const float*)d_in[31];
  const float* pos_b2 = (const float*)d_in[32];
  const float* pos_w3 = (const float*)d_in[33];
  const float* pos_b3 = (const float*)d_in[34];

  float* out = (float*)d_out;
  float* ws = (float*)d_ws;
  float* X1 = ws + WS_X1;
  float* X2 = ws + WS_X2;
  float* X3 = ws + WS_X3;
  float* EMB = ws + WS_EMB;
  float* HS = ws + WS_HS;

  // transpose all matvec weight matrices once per launch
  TPAll ta;
  ta.m[0] = {enc_pw, ws + WS_ENCT, 64, 1024};
  ta.m[1] = {dec_pw, ws + WS_DECT, 1024, 160};
  ta.m[2] = {pos_w1, ws + WS_POS1T, 128, 192};
  ta.m[3] = {pos_w2, ws + WS_POS2T, 128, 128};
  ta.m[4] = {pos_w3, ws + WS_POS3T, 64, 128};
  ta.m[5] = {pri_w1, ws + WS_PRI1T, 128, 130};
  ta.m[6] = {pri_w2, ws + WS_PRI2T, 128, 128};
  ta.m[7] = {pri_w3, ws + WS_PRI3T, 64, 128};
  ta.m[8] = {gru_wih, ws + WS_WIHT, 384, 34};
  ta.m[9] = {gru_whh, ws + WS_WHHT, 384, 128};  // FIX: whh is (384,128), was (128,384)
  hipLaunchKernelGGL(k_transpose, dim3(64, 10), dim3(256), 0, stream, ta);

  // encoder
  k_conv1<<<NF, 256, 0, stream>>>(obs, enc_w1, enc_b1, X1);
  k_conv_s2<32, 16, 16, 64, 4, 4, 4><<<NF, 256, 0, stream>>>(X1, enc_w2, enc_b2, X2);
  k_conv_s2<64, 8, 8, 64, 2, 2, 8><<<NF, 256, 0, stream>>>(X2, enc_w3, enc_b3, X3);
  k_enclin<<<NF, 256, 0, stream>>>(X3, ws + WS_ENCT, enc_pb, EMB);

  // sequential core
  k_rssm<<<NB, 256, 0, stream>>>(EMB, actions, noise,
      ws + WS_POS1T, pos_b1, ws + WS_POS2T, pos_b2, ws + WS_POS3T, pos_b3,
      ws + WS_PRI1T, pri_b1, ws + WS_PRI2T, pri_b2, ws + WS_PRI3T, pri_b3,
      ws + WS_WIHT, ws + WS_WHHT, gru_bih, gru_bhh, HS, out);

  // decoder
  k_declin<<<NF, 256, 0, stream>>>(HS, out + OUT_ZS, ws + WS_DECT, dec_pb, X3);
  k_deconv_s2<64, 4, 4, 64, 4, 4, 8, 1, 0><<<NF, 256, 0, stream>>>(X3, dec_w1, dec_b1, X2);
  k_deconv_s2<64, 8, 8, 32, 4, 8, 8, 1, 0><<<NF, 256, 0, stream>>>(X2, dec_w2, dec_b2, X1);
  k_deconv_s2<32, 16, 16, 1, 1, 4, 32, 2, 1><<<NF, 256, 0, stream>>>(X1, dec_w3, dec_b3, out);
}

// Round 3
// 1423.420 us; speedup vs baseline: 1.3383x; 1.3383x over previous
//
#include <hip/hip_runtime.h>
#include <math.h>

// ---------------- problem dims ----------------
#define NB 32
#define NT 64
#define NA 2
#define NE 64
#define ND 128
#define NS 32
#define NF 2048  // NB*NT frames

// ---------------- output float offsets ----------------
#define OUT_ZS    2097152
#define OUT_PRM   (OUT_ZS + 65536)
#define OUT_PRLS  (OUT_PRM + 65536)
#define OUT_PM    (OUT_PRLS + 65536)
#define OUT_PLS   (OUT_PM + 65536)
#define OUT_HF    (OUT_PLS + 65536)

// ---------------- workspace float offsets (28,038,144 floats = 112.2 MB) ---
#define WS_X1    0          // conv1 out / deconv2 out
#define WS_X2    16777216   // conv2 out / deconv1 out
#define WS_X3    25165824   // conv3 out; after enclin: posl1e+gia; then dec-lin out
#define WS_EMB   27262976   // 2048*64
#define WS_HS    27394048   // 64*32*128 pre-update h per step
#define WS_ENCT  27656192   // enc_pw^T (1024x64)
#define WS_DECT  27721728   // dec_pw^T (160x1024)
// bf16 weight packs (ushort; sizes given in float-equivalents)
#define WS_WP1H  27885568   // 128x128 bf16 (8192 f)
#define WS_WP2   27893760   // 128x128 bf16 (8192 f)
#define WS_WP3   27901952   // 64x128 bf16  (4096 f)
#define WS_WWHH  27906048   // 384x128 bf16 (24576 f)
#define WS_WIHZ  27930624   // 384x32 bf16  (6144 f)
// precomputed step inputs (live in the freed X3 region)
#define WS_POSL1E WS_X3                  // 2048*128
#define WS_GIA    (WS_X3 + 262144)      // 2048*384

// ==================== helpers ====================
__device__ __forceinline__ float eluf(float a) { return (a > 0.f) ? a : expm1f(a); }
__device__ __forceinline__ float sigm(float a) { return 1.f / (1.f + expf(-a)); }
__device__ __forceinline__ unsigned short f2bf(float f) {
  unsigned int u = __float_as_uint(f);
  u += 0x7fffu + ((u >> 16) & 1u);
  return (unsigned short)(u >> 16);
}
template<int N>
__device__ __forceinline__ float bf16dot(const unsigned short* __restrict__ w,
                                         const float* __restrict__ x) {
  float acc = 0.f;
#pragma unroll
  for (int k = 0; k < N; k += 8) {
    uint4 u = *reinterpret_cast<const uint4*>(w + k);
    acc += __uint_as_float(u.x << 16) * x[k + 0];
    acc += __uint_as_float(u.x & 0xffff0000u) * x[k + 1];
    acc += __uint_as_float(u.y << 16) * x[k + 2];
    acc += __uint_as_float(u.y & 0xffff0000u) * x[k + 3];
    acc += __uint_as_float(u.z << 16) * x[k + 4];
    acc += __uint_as_float(u.z & 0xffff0000u) * x[k + 5];
    acc += __uint_as_float(u.w << 16) * x[k + 6];
    acc += __uint_as_float(u.w & 0xffff0000u) * x[k + 7];
  }
  return acc;
}

// ==================== weight transposes (enc/dec projections only) =========
struct TP { const float* src; float* dst; int rows; int cols; };
struct TPAll { TP m[2]; };

__global__ __launch_bounds__(256) void k_transpose(TPAll a) {
  TP tp = a.m[blockIdx.y];
  const int n = tp.rows * tp.cols;
  for (int i = blockIdx.x * 256 + threadIdx.x; i < n; i += gridDim.x * 256) {
    int r = i / tp.cols, c = i - r * tp.cols;
    tp.dst[c * tp.rows + r] = tp.src[i];
  }
}

// ==================== bf16 weight packing ====================
// mode 0: direct; mode 1: src[(i>>7)*192+(i&127)] (pos_w1 h-part);
// mode 2: src[(i>>5)*34+(i&31)] (wih z-part)
struct PK { const float* src; unsigned short* dst; int n; int mode; };
struct PKAll { PK m[5]; };

__global__ __launch_bounds__(256) void k_pack(PKAll a) {
  PK p = a.m[blockIdx.y];
  for (int i = blockIdx.x * 256 + threadIdx.x; i < p.n; i += gridDim.x * 256) {
    float v;
    if (p.mode == 0) v = p.src[i];
    else if (p.mode == 1) v = p.src[(i >> 7) * 192 + (i & 127)];
    else v = p.src[(i >> 5) * 34 + (i & 31)];
    p.dst[i] = f2bf(v);
  }
}

// ==================== encoder conv1: 1x32x32 -> 32x16x16, s2 p1 relu =======
__global__ __launch_bounds__(256) void k_conv1(const float* __restrict__ obs,
    const float* __restrict__ w, const float* __restrict__ bias,
    float* __restrict__ out) {
  __shared__ float sIn[32 * 33];
  __shared__ float sW[512];
  __shared__ float sB[32];
  const int f = blockIdx.x, tid = threadIdx.x;
  const float* in = obs + f * 1024;
  for (int i = tid; i < 1024; i += 256) sIn[(i >> 5) * 33 + (i & 31)] = in[i];
  for (int i = tid; i < 512; i += 256) sW[i] = w[i];
  if (tid < 32) sB[tid] = bias[tid];
  __syncthreads();
  float* outf = out + f * 8192;
  for (int r = tid; r < 512; r += 256) {       // r = oc*16 + oy
    const int oc = r >> 4, oy = r & 15;
    float acc[16];
    const float bv = sB[oc];
#pragma unroll
    for (int j = 0; j < 16; j++) acc[j] = bv;
#pragma unroll
    for (int ky = 0; ky < 4; ky++) {
      const int iy = 2 * oy + ky - 1;
      if (iy < 0 || iy >= 32) continue;
#pragma unroll
      for (int kx = 0; kx < 4; kx++) {
        const float wv = sW[oc * 16 + ky * 4 + kx];
#pragma unroll
        for (int j = 0; j < 16; j++) {
          const int ix = 2 * j + kx - 1;
          if (ix >= 0 && ix < 32) acc[j] += wv * sIn[iy * 33 + ix];
        }
      }
    }
#pragma unroll
    for (int j = 0; j < 16; j++) outf[r * 16 + j] = fmaxf(acc[j], 0.f);
  }
}

// ==================== generic stride-2 conv (k4 p1, relu) ==================
template<int IC, int IH, int IW, int OC, int TOC, int TPX, int CH>
__global__ __launch_bounds__(256) void k_conv_s2(const float* __restrict__ x,
    const float* __restrict__ w, const float* __restrict__ bias,
    float* __restrict__ y) {
  constexpr int OH = IH / 2, OW = IW / 2, NPX = OH * OW;
  constexpr int IWP = IW + 1, OCP = OC + 1;
  constexpr int NPXG = NPX / TPX, NXG = OW / TPX;
  static_assert((OC / TOC) * NPXG == 256, "thread mapping");
  __shared__ float sIn[IC * IH * IWP];
  __shared__ float sW[CH * 16 * OCP];
  const int f = blockIdx.x, tid = threadIdx.x;
  const float* xf = x + (size_t)f * IC * IH * IW;
  for (int i = tid; i < IC * IH * IW; i += 256) {
    const int ic = i / (IH * IW), rem = i - ic * (IH * IW);
    sIn[ic * (IH * IWP) + (rem / IW) * IWP + rem % IW] = xf[i];
  }
  const int ocg = tid / NPXG, pxg = tid - ocg * NPXG;
  const int oc0 = ocg * TOC;
  const int oy = pxg / NXG, ox0 = (pxg - oy * NXG) * TPX;
  float acc[TOC][TPX];
#pragma unroll
  for (int a = 0; a < TOC; a++) {
    const float bv = bias[oc0 + a];
#pragma unroll
    for (int j = 0; j < TPX; j++) acc[a][j] = bv;
  }
  for (int icb = 0; icb < IC; icb += CH) {
    __syncthreads();
    for (int s = tid; s < CH * 16 * OC; s += 256) {
      const int oc = s / (CH * 16), r = s - oc * (CH * 16);
      sW[r * OCP + oc] = w[(oc * IC + icb) * 16 + r];
    }
    __syncthreads();
    for (int icc = 0; icc < CH; icc++) {
      const float* inb = &sIn[(icb + icc) * (IH * IWP)];
      const float* wb = &sW[icc * 16 * OCP];
#pragma unroll
      for (int ky = 0; ky < 4; ky++) {
        const int iy = 2 * oy + ky - 1;
        if (iy < 0 || iy >= IH) continue;
        const float* row = inb + iy * IWP;
#pragma unroll
        for (int kx = 0; kx < 4; kx++) {
          float wv[TOC];
#pragma unroll
          for (int a = 0; a < TOC; a++) wv[a] = wb[(ky * 4 + kx) * OCP + oc0 + a];
#pragma unroll
          for (int j = 0; j < TPX; j++) {
            const int ix = 2 * (ox0 + j) + kx - 1;
            if (ix >= 0 && ix < IW) {
              const float xv = row[ix];
#pragma unroll
              for (int a = 0; a < TOC; a++) acc[a][j] += wv[a] * xv;
            }
          }
        }
      }
    }
  }
  float* yf = y + (size_t)f * OC * NPX;
#pragma unroll
  for (int a = 0; a < TOC; a++)
#pragma unroll
    for (int j = 0; j < TPX; j++)
      yf[(oc0 + a) * NPX + oy * OW + ox0 + j] = fmaxf(acc[a][j], 0.f);
}

// ==================== generic stride-2 deconv (ConvTranspose2d k4 s2 p1) ===
template<int IC, int IH, int IW, int OC, int TOC, int TPX, int CH, int ACT, int REMAP>
__global__ __launch_bounds__(256) void k_deconv_s2(const float* __restrict__ x,
    const float* __restrict__ w, const float* __restrict__ bias,
    float* __restrict__ y) {
  constexpr int OH = IH * 2, OW = IW * 2, NPX = OH * OW;
  constexpr int IWP = IW + 1, OCP = OC + 1;
  constexpr int NQ = (OW / 2) / TPX;
  constexpr int NPXG = OH * 2 * NQ;
  static_assert((OC / TOC) * NPXG == 256, "thread mapping");
  __shared__ float sIn[IC * IH * IWP];
  __shared__ float sW[CH * 16 * OCP];
  const int f = blockIdx.x, tid = threadIdx.x;
  const float* xf = x + (size_t)f * IC * IH * IW;
  for (int i = tid; i < IC * IH * IW; i += 256) {
    const int ic = i / (IH * IW), rem = i - ic * (IH * IW);
    sIn[ic * (IH * IWP) + (rem / IW) * IWP + rem % IW] = xf[i];
  }
  const int ocg = tid / NPXG, pxg = tid - ocg * NPXG;
  const int oc0 = ocg * TOC;
  const int oy = pxg / (2 * NQ);
  const int rem2 = pxg - oy * (2 * NQ);
  const int c = rem2 / NQ, q = rem2 - c * NQ;
  const int py = (oy + 1) & 1, pc = (c + 1) & 1;
  float acc[TOC][TPX];
#pragma unroll
  for (int a = 0; a < TOC; a++) {
    const float bv = bias[oc0 + a];
#pragma unroll
    for (int j = 0; j < TPX; j++) acc[a][j] = bv;
  }
  for (int icb = 0; icb < IC; icb += CH) {
    __syncthreads();
    {
      const float* wb = w + (size_t)icb * OC * 16;
      for (int s = tid; s < CH * OC * 16; s += 256) {
        const int icc = s / (OC * 16), r = s - icc * (OC * 16);
        const int oc = r / 16, tap = r & 15;
        sW[(icc * 16 + tap) * OCP + oc] = wb[s];
      }
    }
    __syncthreads();
    for (int icc = 0; icc < CH; icc++) {
      const float* inb = &sIn[(icb + icc) * (IH * IWP)];
      const float* wb = &sW[icc * 16 * OCP];
#pragma unroll
      for (int t2 = 0; t2 < 2; t2++) {
        const int ky = py + 2 * t2;
        const int iy = (oy + 1 - ky) >> 1;
        if (iy < 0 || iy >= IH) continue;
        const float* row = inb + iy * IWP;
#pragma unroll
        for (int t3 = 0; t3 < 2; t3++) {
          const int kx = pc + 2 * t3;
          const int ixb = (c + 1 - kx) >> 1;
          float wv[TOC];
#pragma unroll
          for (int a = 0; a < TOC; a++) wv[a] = wb[(ky * 4 + kx) * OCP + oc0 + a];
#pragma unroll
          for (int j = 0; j < TPX; j++) {
            const int ix = ixb + q * TPX + j;
            if (ix >= 0 && ix < IW) {
              const float xv = row[ix];
#pragma unroll
              for (int a = 0; a < TOC; a++) acc[a][j] += wv[a] * xv;
            }
          }
        }
      }
    }
  }
  int fo = f;
  if (REMAP) fo = (f & (NB - 1)) * NT + (f >> 5);
  float* yf = y + (size_t)fo * OC * NPX;
#pragma unroll
  for (int a = 0; a < TOC; a++)
#pragma unroll
    for (int j = 0; j < TPX; j++) {
      float v = acc[a][j];
      if (ACT == 1) v = fmaxf(v, 0.f);
      if (ACT == 2) v = 1.f / (1.f + expf(-v));
      yf[(oc0 + a) * NPX + oy * OW + (c + 2 * (q * TPX + j))] = v;
    }
}

// ==================== encoder linear: (2048,1024) -> (2048,64) =============
__global__ __launch_bounds__(256) void k_enclin(const float* __restrict__ x,
    const float* __restrict__ wT, const float* __restrict__ bias,
    float* __restrict__ emb) {
  __shared__ float sX[1024];
  __shared__ float sP[256];
  const int f = blockIdx.x, tid = threadIdx.x;
  for (int i = tid; i < 1024; i += 256) sX[i] = x[(size_t)f * 1024 + i];
  __syncthreads();
  const int o = tid & 63, s = tid >> 6;
  float acc = 0.f;
  const int k0 = s * 256;
  for (int k = k0; k < k0 + 256; k++) acc += wT[k * 64 + o] * sX[k];
  sP[tid] = acc;
  __syncthreads();
  if (tid < 64)
    emb[(size_t)f * 64 + tid] =
        sP[tid] + sP[tid + 64] + sP[tid + 128] + sP[tid + 192] + bias[tid];
}

// ==================== precompute: posl1e (e-part) and gia (a-part) =========
// f = b*64+t
__global__ __launch_bounds__(512) void k_pre(const float* __restrict__ emb,
    const float* __restrict__ act, const float* __restrict__ pw1,
    const float* __restrict__ pb1, const float* __restrict__ wih,
    const float* __restrict__ bih, float* __restrict__ posl1e,
    float* __restrict__ gia) {
  __shared__ float sE[64];
  __shared__ float sA2[2];
  const int f = blockIdx.x, tid = threadIdx.x;
  if (tid < 64) sE[tid] = emb[(size_t)f * 64 + tid];
  else if (tid < 66) sA2[tid - 64] = act[(size_t)f * 2 + (tid - 64)];
  __syncthreads();
  if (tid < 128) {
    float a = pb1[tid];
    const float* wr = pw1 + tid * 192 + 128;
    for (int k = 0; k < 64; k++) a += wr[k] * sE[k];
    posl1e[(size_t)f * 128 + tid] = a;
  } else {
    const int j = tid - 128;  // 0..383
    gia[(size_t)f * 384 + j] =
        bih[j] + wih[j * 34 + 32] * sA2[0] + wih[j * 34 + 33] * sA2[1];
  }
}

// ==================== recurrent core (posterior chain + GRU only) ==========
// one block per batch element; bf16 weights, fp32 activations/accum.
__global__ __launch_bounds__(512) void k_rssm2(
    const float* __restrict__ posl1e, const float* __restrict__ gia,
    const float* __restrict__ noise,
    const unsigned short* __restrict__ wp1h, const unsigned short* __restrict__ wp2,
    const unsigned short* __restrict__ wp3, const unsigned short* __restrict__ wwhh,
    const unsigned short* __restrict__ wihz,
    const float* __restrict__ pb2, const float* __restrict__ pb3,
    const float* __restrict__ bhh,
    float* __restrict__ hs, float* __restrict__ out) {
  const int b = blockIdx.x, tid = threadIdx.x;
  __shared__ float sH[128], sL1[128], sL2[128];
  __shared__ float sGh[384], sGi[384];
  __shared__ float sPm[32], sPls[32], sZ[32], sEps[32];
  __shared__ float sPart[512];
  if (tid < 128) {
    sH[tid] = 0.f;
    hs[(size_t)b * 128 + tid] = 0.f;  // hs[t=0][b]
  } else if (tid < 160) {
    sEps[tid - 128] = noise[(size_t)b * 32 + (tid - 128)];  // t=0
  }
  __syncthreads();
  for (int t = 0; t < 64; ++t) {
    const int f = b * 64 + t;
    // ---- stage A: pos-l1 h-part (128 outs) + gh (384 outs), K=128
    if (tid < 128) {
      float a = posl1e[(size_t)f * 128 + tid] + bf16dot<128>(wp1h + tid * 128, sH);
      sL1[tid] = eluf(a);
    } else {
      const int j = tid - 128;
      sGh[j] = bhh[j] + bf16dot<128>(wwhh + j * 128, sH);
    }
    __syncthreads();
    // ---- stage B: pos-l2, 128 outs, K-split 4x32
    {
      const int o = tid & 127, c = tid >> 7;
      sPart[tid] = bf16dot<32>(wp2 + o * 128 + c * 32, sL1 + c * 32);
    }
    __syncthreads();
    if (tid < 128)
      sL2[tid] = eluf(pb2[tid] + sPart[tid] + sPart[tid + 128] +
                      sPart[tid + 256] + sPart[tid + 384]);
    __syncthreads();
    // ---- stage C: pos-l3, 64 outs, K-split 8x16
    {
      const int o = tid & 63, c = tid >> 6;
      sPart[tid] = bf16dot<16>(wp3 + o * 128 + c * 16, sL2 + c * 16);
    }
    __syncthreads();
    if (tid < 64) {
      float a = pb3[tid];
#pragma unroll
      for (int c = 0; c < 8; c++) a += sPart[tid + c * 64];
      if (tid < 32) sPm[tid] = a;
      else sPls[tid - 32] = fminf(fmaxf(a, -5.f), 2.f);
    }
    __syncthreads();
    // ---- z + latent outputs (pm/pls/zs)
    if (tid < 32) {
      const float z = sPm[tid] + expf(sPls[tid]) * sEps[tid];
      sZ[tid] = z;
      const int o = f * 32 + tid;
      out[OUT_ZS + o] = z;
      out[OUT_PM + o] = sPm[tid];
      out[OUT_PLS + o] = sPls[tid];
    }
    __syncthreads();
    // ---- stage D: gi z-part, 384 outs, K=32
    if (tid < 384) sGi[tid] = gia[(size_t)f * 384 + tid] + bf16dot<32>(wihz + tid * 32, sZ);
    __syncthreads();
    // ---- stage E: GRU gates + h update + hs store + eps prefetch
    if (tid < 128) {
      const float r = sigm(sGi[tid] + sGh[tid]);
      const float u = sigm(sGi[128 + tid] + sGh[128 + tid]);
      const float n = tanhf(sGi[256 + tid] + r * sGh[256 + tid]);
      const float hn = (1.f - u) * n + u * sH[tid];
      sH[tid] = hn;
      if (t < 63) hs[(size_t)((t + 1) * 32 + b) * 128 + tid] = hn;
    } else if (tid < 160 && t < 63) {
      sEps[tid - 128] = noise[(size_t)((t + 1) * 32 + b) * 32 + (tid - 128)];
    }
    __syncthreads();
  }
  if (tid < 128) out[OUT_HF + b * 128 + tid] = sH[tid];
}

// ==================== prior chain, batched post-hoc over all (t,b) =========
// f = t*32+b (matches hs layout)
__global__ __launch_bounds__(128) void k_pri(const float* __restrict__ hs,
    const float* __restrict__ act,
    const float* __restrict__ qw1, const float* __restrict__ qb1,
    const float* __restrict__ qw2, const float* __restrict__ qb2,
    const float* __restrict__ qw3, const float* __restrict__ qb3,
    float* __restrict__ out) {
  __shared__ float sV[128], sW[128];
  __shared__ float sA2[2];
  const int f = blockIdx.x, tid = threadIdx.x;
  const int t = f >> 5, b = f & 31;
  sV[tid] = hs[(size_t)f * 128 + tid];
  if (tid < 2) sA2[tid] = act[(size_t)(b * 64 + t) * 2 + tid];
  __syncthreads();
  {
    const float* wr = qw1 + tid * 130;
    float a = qb1[tid];
    for (int k = 0; k < 128; k++) a += wr[k] * sV[k];
    a += wr[128] * sA2[0] + wr[129] * sA2[1];
    sW[tid] = eluf(a);
  }
  __syncthreads();
  {
    const float* wr = qw2 + tid * 128;
    float a = qb2[tid];
    for (int k = 0; k < 128; k++) a += wr[k] * sW[k];
    sV[tid] = eluf(a);
  }
  __syncthreads();
  if (tid < 64) {
    const float* wr = qw3 + tid * 128;
    float a = qb3[tid];
    for (int k = 0; k < 128; k++) a += wr[k] * sV[k];
    const int o = (b * 64 + t) * 32;
    if (tid < 32) out[OUT_PRM + o + tid] = a;
    else out[OUT_PRLS + o + tid - 32] = fminf(fmaxf(a, -5.f), 2.f);
  }
}

// ==================== decoder linear: (2048,160) -> (2048,1024) ============
__global__ __launch_bounds__(256) void k_declin(const float* __restrict__ hs,
    const float* __restrict__ zs, const float* __restrict__ wT,
    const float* __restrict__ bias, float* __restrict__ y) {
  __shared__ float sX[160];
  const int f = blockIdx.x, tid = threadIdx.x;
  const int t = f >> 5, b = f & 31;
  if (tid < 128) sX[tid] = hs[(size_t)(t * 32 + b) * 128 + tid];
  else if (tid < 160) sX[tid] = zs[(size_t)(b * 64 + t) * 32 + (tid - 128)];
  __syncthreads();
  float acc[4];
#pragma unroll
  for (int i = 0; i < 4; i++) acc[i] = bias[i * 256 + tid];
  for (int k = 0; k < 160; k++) {
    const float xv = sX[k];
#pragma unroll
    for (int i = 0; i < 4; i++) acc[i] += wT[k * 1024 + i * 256 + tid] * xv;
  }
#pragma unroll
  for (int i = 0; i < 4; i++) y[(size_t)f * 1024 + i * 256 + tid] = acc[i];
}

// ==================== launch ====================
extern "C" void kernel_launch(void* const* d_in, const int* in_sizes, int n_in,
                              void* d_out, int out_size, void* d_ws, size_t ws_size,
                              hipStream_t stream) {
  const float* obs = (const float*)d_in[0];
  const float* actions = (const float*)d_in[1];
  const float* noise = (const float*)d_in[2];
  const float* enc_w1 = (const float*)d_in[3];
  const float* enc_b1 = (const float*)d_in[4];
  const float* enc_w2 = (const float*)d_in[5];
  const float* enc_b2 = (const float*)d_in[6];
  const float* enc_w3 = (const float*)d_in[7];
  const float* enc_b3 = (const float*)d_in[8];
  const float* enc_pw = (const float*)d_in[9];
  const float* enc_pb = (const float*)d_in[10];
  const float* dec_pw = (const float*)d_in[11];
  const float* dec_pb = (const float*)d_in[12];
  const float* dec_w1 = (const float*)d_in[13];
  const float* dec_b1 = (const float*)d_in[14];
  const float* dec_w2 = (const float*)d_in[15];
  const float* dec_b2 = (const float*)d_in[16];
  const float* dec_w3 = (const float*)d_in[17];
  const float* dec_b3 = (const float*)d_in[18];
  const float* gru_wih = (const float*)d_in[19];
  const float* gru_whh = (const float*)d_in[20];
  const float* gru_bih = (const float*)d_in[21];
  const float* gru_bhh = (const float*)d_in[22];
  const float* pri_w1 = (const float*)d_in[23];
  const float* pri_b1 = (const float*)d_in[24];
  const float* pri_w2 = (const float*)d_in[25];
  const float* pri_b2 = (const float*)d_in[26];
  const float* pri_w3 = (const float*)d_in[27];
  const float* pri_b3 = (const float*)d_in[28];
  const float* pos_w1 = (const float*)d_in[29];
  const float* pos_b1 = (const float*)d_in[30];
  const float* pos_w2 = (const float*)d_in[31];
  const float* pos_b2 = (const float*)d_in[32];
  const float* pos_w3 = (const float*)d_in[33];
  const float* pos_b3 = (const float*)d_in[34];

  float* out = (float*)d_out;
  float* ws = (float*)d_ws;
  float* X1 = ws + WS_X1;
  float* X2 = ws + WS_X2;
  float* X3 = ws + WS_X3;
  float* EMB = ws + WS_EMB;
  float* HS = ws + WS_HS;
  float* POSL1E = ws + WS_POSL1E;
  float* GIA = ws + WS_GIA;
  unsigned short* WP1H = (unsigned short*)(ws + WS_WP1H);
  unsigned short* WP2 = (unsigned short*)(ws + WS_WP2);
  unsigned short* WP3 = (unsigned short*)(ws + WS_WP3);
  unsigned short* WWHH = (unsigned short*)(ws + WS_WWHH);
  unsigned short* WIHZ = (unsigned short*)(ws + WS_WIHZ);

  // transposes for enc/dec projections
  TPAll ta;
  ta.m[0] = {enc_pw, ws + WS_ENCT, 64, 1024};
  ta.m[1] = {dec_pw, ws + WS_DECT, 1024, 160};
  hipLaunchKernelGGL(k_transpose, dim3(64, 2), dim3(256), 0, stream, ta);

  // bf16-pack in-loop recurrence weights (rows already contiguous)
  PKAll pa;
  pa.m[0] = {pos_w1, WP1H, 128 * 128, 1};   // h-part of pos_w1 (128,192)
  pa.m[1] = {pos_w2, WP2, 128 * 128, 0};
  pa.m[2] = {pos_w3, WP3, 64 * 128, 0};
  pa.m[3] = {gru_whh, WWHH, 384 * 128, 0};
  pa.m[4] = {gru_wih, WIHZ, 384 * 32, 2};   // z-part of wih (384,34)
  hipLaunchKernelGGL(k_pack, dim3(64, 5), dim3(256), 0, stream, pa);

  // encoder
  k_conv1<<<NF, 256, 0, stream>>>(obs, enc_w1, enc_b1, X1);
  k_conv_s2<32, 16, 16, 64, 4, 4, 4><<<NF, 256, 0, stream>>>(X1, enc_w2, enc_b2, X2);
  k_conv_s2<64, 8, 8, 64, 2, 2, 8><<<NF, 256, 0, stream>>>(X2, enc_w3, enc_b3, X3);
  k_enclin<<<NF, 256, 0, stream>>>(X3, ws + WS_ENCT, enc_pb, EMB);

  // per-step input precompute (X3 region is dead after enclin)
  k_pre<<<NF, 512, 0, stream>>>(EMB, actions, pos_w1, pos_b1, gru_wih, gru_bih,
                                POSL1E, GIA);

  // sequential core (posterior + GRU only)
  k_rssm2<<<NB, 512, 0, stream>>>(POSL1E, GIA, noise, WP1H, WP2, WP3, WWHH, WIHZ,
                                  pos_b2, pos_b3, gru_bhh, HS, out);

  // prior chain post-hoc (fully parallel)
  k_pri<<<NF, 128, 0, stream>>>(HS, actions, pri_w1, pri_b1, pri_w2, pri_b2,
                                pri_w3, pri_b3, out);

  // decoder
  k_declin<<<NF, 256, 0, stream>>>(HS, out + OUT_ZS, ws + WS_DECT, dec_pb, X3);
  k_deconv_s2<64, 4, 4, 64, 4, 4, 8, 1, 0><<<NF, 256, 0, stream>>>(X3, dec_w1, dec_b1, X2);
  k_deconv_s2<64, 8, 8, 32, 4, 8, 8, 1, 0><<<NF, 256, 0, stream>>>(X2, dec_w2, dec_b2, X1);
  k_deconv_s2<32, 16, 16, 1, 1, 4, 32, 2, 1><<<NF, 256, 0, stream>>>(X1, dec_w3, dec_b3, out);
}